// Round 9
// baseline (6022.171 us; speedup 1.0000x reference)
//
#include <hip/hip_runtime.h>
#include <hip/hip_bf16.h>
#include <hip/hip_fp16.h>

// Hypernetwork RNN scan. B=16, N=2048, M=H=64, L*E=1024, Cout=256.
// Round 22: i-SLICE ownership + final-value exchange.
// R21 lesson: poll traffic intensity slows LLC turnover (pipelined polls
// regressed). R13 lesson: exchanging PARTIALS puts an assemble phase after
// the RTT on the serial chain. This round: WG (b,s) OWNS output slice
// i in [16s,16s+16): holds Wd[*][i-slice][*] (128 KB = 64 VGPR/thread),
// computes its 16 m values completely, publishes ONE 64-B line of tagged
// (tag|f16 pair) u64s; peers poll 3 lines with 24 lanes (8x less poll
// traffic than R13). Detection IS payload; no assemble phase; each m[i]
// has a single owner so cross-WG bit-consistency is automatic.
// Per-step: V (64 dot2/thr from regs) + henc (8 dot2, 4-part tree) ->
// hw -> per-wave shfl_xor butterfly over h -> aux (Wdb*m, bdec*hb on
// lane groups) -> sigmoid -> f2h -> publish. 3 barriers.
//   K1 cvt: Wd->f16 i-slice layout; enc rows->f16 pairs; dec_w->bf16
//   K2 build_T (f32, 8 MB), K3 build_P (f32, 16 MB)
//   K4 recur: 64 WGs = 16 batches x 4 i-slices; Wd in VGPRs
//   K5 loss:  parallel logits/LSE/NLL over the f16 m history

typedef unsigned int uint_t;
typedef unsigned short us_t;
typedef unsigned long long u64_t;
typedef _Float16 h2_t __attribute__((ext_vector_type(2)));

__device__ __forceinline__ us_t f2bf(float f) {
    uint_t u = __float_as_uint(f);
    uint_t r = u + 0x7fffu + ((u >> 16) & 1u);   // RNE
    return (us_t)(r >> 16);
}
__device__ __forceinline__ float bflo(uint_t u) { return __uint_as_float(u << 16); }
__device__ __forceinline__ float bfhi(uint_t u) { return __uint_as_float(u & 0xffff0000u); }

__device__ __forceinline__ us_t f2h(float f) {
    __half h = __float2half(f);                  // RNE
    return *reinterpret_cast<us_t*>(&h);
}
__device__ __forceinline__ float h2f(us_t s) {
    __half h = *reinterpret_cast<__half*>(&s);
    return __half2float(h);
}
__device__ __forceinline__ h2_t u2h2(uint_t u) {
    union { uint_t u; h2_t h; } x; x.u = u; return x.h;
}

#if __has_builtin(__builtin_amdgcn_fdot2)
__device__ __forceinline__ float dot2f(uint_t a, uint_t b, float c) {
    return __builtin_amdgcn_fdot2(u2h2(a), u2h2(b), c, false);
}
#else
__device__ __forceinline__ float dot2f(uint_t a, uint_t b, float c) {
    h2_t x = u2h2(a), y = u2h2(b);
    return c + (float)x.x * (float)y.x + (float)x.y * (float)y.y;
}
#endif

#define DOT4C(q, mc, acc)                                               \
    acc = dot2f(q.x, mc.x, acc);                                        \
    acc = dot2f(q.y, mc.y, acc);                                        \
    acc = dot2f(q.z, mc.z, acc);                                        \
    acc = dot2f(q.w, mc.w, acc);

// ---------------- K1: convert/swizzle weights ----------------
// WdG [s<4][c<16][tid<512][e<8] f16 (uint4 at (s*16+c)*512+tid):
//     tid -> h=tid&63, ip=tid>>6;  c -> iq=c>>3, jp=c&7
//     i = 16s + 2*ip + iq,  j = jp*8 + e;  val = Wd[h][i*64 + j]
// decwY [mm<64][lane<64][k<4] bf16: val = decw[mm*256 + k*64 + lane]
// EWmG us_t[8192]: [pj<32][h2<128][half<2]:
//     j = (pj>>3)*16 + (pj&7)*2 + half; val = enc_row(j, h2)
__global__ void cvt_kernel(const float* __restrict__ Wdecw,
                           const float* __restrict__ decw,
                           const float* __restrict__ Wencw,
                           const float* __restrict__ bencw,
                           us_t* __restrict__ WdG, us_t* __restrict__ decwY,
                           us_t* __restrict__ EWmG) {
    int o = blockIdx.x * 256 + threadIdx.x;
    if (o < 262144) {
        int s = o >> 16;
        int r = o & 65535;
        int e = r & 7;
        int tq = (r >> 3) & 511;
        int c = r >> 12;
        int h = tq & 63, ip = tq >> 6;
        int iq = c >> 3, jp = c & 7;
        int i = 16 * s + 2 * ip + iq;
        int j = jp * 8 + e;
        WdG[o] = f2h(Wdecw[h * 4096 + i * 64 + j]);
    } else if (o < 278528) {
        int oo = o - 262144;
        int k = oo & 3, lane = (oo >> 2) & 63, mm = oo >> 8;
        decwY[oo] = f2bf(decw[mm * 256 + k * 64 + lane]);
    } else if (o < 286720) {
        int o2 = o - 278528;           // < 8192
        int half = o2 & 1;
        int h2 = (o2 >> 1) & 127;
        int pj = o2 >> 8;
        int j = (pj >> 3) * 16 + (pj & 7) * 2 + half;
        float v = (h2 < 64) ? Wencw[j * 64 + h2] : bencw[j * 64 + (h2 - 64)];
        EWmG[o2] = f2h(v);
    }
}

// ---------------- K2: token contribution table ----------------
__global__ void build_T(const float* __restrict__ emb, const float* __restrict__ Wencw,
                        const float* __restrict__ bencw, float* __restrict__ T) {
    int l = blockIdx.x >> 8, v = blockIdx.x & 255, h2 = threadIdx.x;  // h2 < 128
    float acc = 0.f;
#pragma unroll
    for (int e = 0; e < 16; ++e) {
        int d = 64 + l * 16 + e;
        float w = (h2 < 64) ? Wencw[d * 64 + h2] : bencw[d * 64 + (h2 - 64)];
        acc += emb[v * 16 + e] * w;
    }
    T[blockIdx.x * 128 + h2] = acc;
}

// ---------------- K3: window precompute P (f32) ----------------
__global__ void build_P(const float* __restrict__ T, const int* __restrict__ x0,
                        const float* __restrict__ Wencb, const float* __restrict__ bencb,
                        float* __restrict__ P) {
    int t = blockIdx.x >> 4, b = blockIdx.x & 15, h2 = threadIdx.x;  // h2 < 128
    float acc = (h2 < 64) ? Wencb[h2] : bencb[h2 - 64];
    for (int l = 0; l < 64; ++l) {
        int p = t + l;
        int v = (p < 64) ? 0 : x0[b * 2048 + (p - 64)];
        acc += T[(l * 256 + v) * 128 + h2];
    }
    P[blockIdx.x * 128 + h2] = acc;
}

// ---------------- K4: sequential recurrence (i-slice owner) ----------
// grid 64: b = blk&15, s = blk>>4. 512 thr. ~23 KB LDS.
// Thread (ip=tid>>6, h=tid&63) computes V[h][i0], V[h][i1],
// i0 = 16s+2ip, i1 = i0+1, from 16 uint4 of register-resident Wd.
__global__ __launch_bounds__(512, 1) void recur(
    const float* __restrict__ bdecw, const float* __restrict__ bdecb,
    const float* __restrict__ Wdecb, const us_t* __restrict__ WdG,
    const us_t* __restrict__ EWmG, const float* __restrict__ P,
    uint_t* __restrict__ mh32, u64_t* __restrict__ pxb) {
    const int b = blockIdx.x & 15, s = blockIdx.x >> 4;
    const int tid = threadIdx.x;

    __shared__ __align__(16) uint_t ew2[4096];   // 16 KB [pj<32][h2<128] pairs
    __shared__ uint_t wdb2[512];                 // [jj<32][il<16] Wdb pairs (own i)
    __shared__ uint_t bdec2o[512];               // [hh<32][il<16] bdec pairs (own i)
    __shared__ float  hp_s[512];                 // [part<4][h2<128] henc partials
    __shared__ float  hw_s[64];
    __shared__ uint_t hb2_s[32];                 // packed f16 hb pairs
    __shared__ __align__(16) uint_t m2_s[32];    // packed f16 m pairs (full m)
    __shared__ float  bias_s[16];                // own-slice bias

    const int h = tid & 63, ip = tid >> 6;
    const int lane = tid & 63, w = tid >> 6;
    const int h2p = tid & 127, part = tid >> 7;

    // ---- init ----
    uint4 wreg[16];
    {
        const uint4* g4 = (const uint4*)WdG + s * 8192;
#pragma unroll
        for (int c = 0; c < 16; ++c) wreg[c] = g4[c * 512 + tid];
    }
    {
        const uint_t* g = (const uint_t*)EWmG;   // 4096 u32 pairs
        for (int k = tid; k < 4096; k += 512) ew2[k] = g[k];
    }
    if (tid < 512) {
        int jj = tid >> 4, il = tid & 15;
        int i = 16 * s + il;
        wdb2[tid] = (uint_t)f2h(Wdecb[i * 64 + 2 * jj])
                  | ((uint_t)f2h(Wdecb[i * 64 + 2 * jj + 1]) << 16);
        bdec2o[tid] = (uint_t)f2h(bdecw[(2 * jj) * 64 + i])
                    | ((uint_t)f2h(bdecw[(2 * jj + 1) * 64 + i]) << 16);
    }
    if (tid < 16) bias_s[tid] = bdecb[16 * s + tid];
    if (tid < 32) m2_s[tid] = 0u;                // m_0 = 0 (no t=0 exchange)
    __syncthreads();

    float preg = 0.f;
    if (tid < 128) preg = P[b * 128 + tid];      // t = 0

    const uint4* m4 = (const uint4*)m2_s;

    for (int t = 0; t < 2048; ++t) {
        // ---- poll peers' m_t slices (t >= 1); wave 0 only ----
        if (t > 0 && w == 0) {
            int lx = (lane < 24) ? lane : 0;     // lanes >=24 mirror lane 0
            int pi = lx >> 3, k = lx & 7;
            int ps = pi + (pi >= s ? 1 : 0);
            const u64_t* src = pxb + ((t & 1) * 16 + b) * 32 + ps * 8 + k;
            u64_t v;
            for (;;) {
                v = __hip_atomic_load(src, __ATOMIC_RELAXED,
                                      __HIP_MEMORY_SCOPE_AGENT);
                if (__ballot((uint_t)(v >> 32) == (uint_t)t) == ~0ull) break;
            }
            if (lane < 24) m2_s[ps * 8 + k] = (uint_t)v;
        }
        __syncthreads();   // bar A: full m_t in m2_s

        // ---- P prefetch for t+1 ----
        float pnext = 0.f;
        int tp = (t < 2047) ? (t + 1) : 2047;
        if (tid < 128) pnext = P[(tp * 16 + b) * 128 + tid];

        // ---- V: 64 dot2 from registers (m broadcast from LDS) ----
        float a0 = 0.f, a1 = 0.f;
#pragma unroll
        for (int jp = 0; jp < 8; ++jp) {
            uint4 mc = m4[jp];
            DOT4C(wreg[jp], mc, a0);             // iq = 0 -> i0
            DOT4C(wreg[8 + jp], mc, a1);         // iq = 1 -> i1
        }

        // ---- henc partial (4-way j-split over all 512 threads) ----
        {
            float hp = 0.f;
#pragma unroll
            for (int jjl = 0; jjl < 8; ++jjl)
                hp = dot2f(ew2[(part * 8 + jjl) * 128 + h2p],
                           m2_s[part * 8 + jjl], hp);
            hp_s[part * 128 + h2p] = hp;
        }
        __syncthreads();   // bar B: henc partials ready

        // ---- hw / hb (tid < 128) ----
        if (tid < 128) {
            float acc = preg + ((hp_s[h2p] + hp_s[128 + h2p])
                              + (hp_s[256 + h2p] + hp_s[384 + h2p]));
            float sg = 1.f / (1.f + __expf(-acc));
            if (tid < 64) {
                hw_s[tid] = sg;
            } else {
                int l = tid - 64;
                float vlo = __shfl(sg, (l & 31) * 2, 64);
                float vhi = __shfl(sg, (l & 31) * 2 + 1, 64);
                if (l < 32)
                    hb2_s[l] = (uint_t)f2h(vlo) | ((uint_t)f2h(vhi) << 16);
            }
        }
        preg = pnext;
        __syncthreads();   // bar C: hw_s / hb2_s ready

        // ---- per-wave: butterfly h-reduce, aux terms, assemble, publish ----
        {
            float hwv = hw_s[h];
            float s0 = hwv * a0;
            float s1 = hwv * a1;
#pragma unroll
            for (int o = 32; o > 0; o >>= 1) {
                s0 += __shfl_xor(s0, o, 64);
                s1 += __shfl_xor(s1, o, 64);
            }
            // aux: lane groups g = lane>>4: {wm[i0], wm[i1], hb[i0], hb[i1]}
            int g = lane >> 4;
            int ilq = 2 * ip + (g & 1);
            const uint_t* tabp = (g < 2) ? wdb2 : bdec2o;
            const uint_t* vecp = (g < 2) ? m2_s : hb2_s;
            float aux = 0.f;
#pragma unroll
            for (int jj = 0; jj < 32; ++jj)
                aux = dot2f(tabp[jj * 16 + ilq], vecp[jj], aux);
            float wmA = __shfl(aux, 0, 64);
            float wmB = __shfl(aux, 16, 64);
            float hbA = __shfl(aux, 32, 64);
            float hbB = __shfl(aux, 48, 64);
            float m0 = 1.f / (1.f + __expf(-((s0 + wmA + hbA) + bias_s[2 * ip])));
            float m1 = 1.f / (1.f + __expf(-((s1 + wmB + hbB) + bias_s[2 * ip + 1])));
            us_t n0 = f2h(m0), n1 = f2h(m1);
            if (lane == 0) {
                uint_t pk = (uint_t)n0 | ((uint_t)n1 << 16);
                int jg = 8 * s + ip;             // global pair index
                m2_s[jg] = pk;
                mh32[(t * 16 + b) * 32 + jg] = pk;   // history = m_{t+1}
                u64_t pay = ((u64_t)(uint_t)(t + 1) << 32) | (u64_t)pk;
                __hip_atomic_store(pxb + (((t + 1) & 1) * 16 + b) * 32 + s * 8 + ip,
                                   pay, __ATOMIC_RELAXED, __HIP_MEMORY_SCOPE_AGENT);
            }
        }
        // no barrier here: wave 0 proceeds to poll (parity flips);
        // bar A next iteration orders all m2_s writes before reads.
    }
}

// ---------------- K5: parallel loss (reads f16 m history) ----------------
__global__ __launch_bounds__(256) void loss_kernel(
    const us_t* __restrict__ mhb, const us_t* __restrict__ decwY,
    const float* __restrict__ decb, const int* __restrict__ x0,
    float* __restrict__ out) {
    __shared__ __align__(16) us_t dw[16384];   // [mm][lane][k<4] bf16
    const int tid = threadIdx.x;
    {
        const uint4* g4 = (const uint4*)decwY;
        uint4* l4 = (uint4*)dw;
        for (int k = tid; k < 2048; k += 256) l4[k] = g4[k];
    }
    __syncthreads();
    const int lane = tid & 63, wv = tid >> 6;
    const uint2* dwu2 = (const uint2*)dw;
    float b0 = decb[lane], b1 = decb[lane + 64];
    float b2 = decb[lane + 128], b3 = decb[lane + 192];
    for (int r = 0; r < 8; ++r) {
        int row = blockIdx.x * 32 + wv * 8 + r;
        float mL = h2f(mhb[row * 64 + lane]);
        float l0 = b0, l1 = b1, l2 = b2, l3 = b3;
#pragma unroll
        for (int mm = 0; mm < 64; ++mm) {
            float mv = __shfl(mL, mm, 64);
            uint2 q = dwu2[mm * 64 + lane];
            l0 += mv * bflo(q.x);
            l1 += mv * bfhi(q.x);
            l2 += mv * bflo(q.y);
            l3 += mv * bfhi(q.y);
        }
        float mx = fmaxf(fmaxf(l0, l1), fmaxf(l2, l3));
#pragma unroll
        for (int o = 32; o > 0; o >>= 1) mx = fmaxf(mx, __shfl_xor(mx, o, 64));
        float se = __expf(l0 - mx) + __expf(l1 - mx) + __expf(l2 - mx) + __expf(l3 - mx);
#pragma unroll
        for (int o = 32; o > 0; o >>= 1) se += __shfl_xor(se, o, 64);
        float lse = mx + __logf(se);
        int t = row >> 4, bb = row & 15;
        int y = x0[bb * 2048 + t];
        int hi = y >> 6;
        float cand = hi == 0 ? l0 : (hi == 1 ? l1 : (hi == 2 ? l2 : l3));
        float ly = __shfl(cand, y & 63, 64);
        if (lane == 0) out[row] = (lse - ly) * 1.4426950408889634f;
    }
}

extern "C" void kernel_launch(void* const* d_in, const int* in_sizes, int n_in,
                              void* d_out, int out_size, void* d_ws, size_t ws_size,
                              hipStream_t stream) {
    const int*   x0    = (const int*)d_in[0];
    const float* emb   = (const float*)d_in[1];
    const float* Wencw = (const float*)d_in[2];
    const float* Wencb = (const float*)d_in[3];
    const float* Wdecw = (const float*)d_in[4];
    const float* Wdecb = (const float*)d_in[5];
    const float* bencw = (const float*)d_in[6];
    const float* bencb = (const float*)d_in[7];
    const float* bdecw = (const float*)d_in[8];
    const float* bdecb = (const float*)d_in[9];
    const float* decw  = (const float*)d_in[10];
    const float* decb  = (const float*)d_in[11];
    float* out = (float*)d_out;

    char* ws = (char*)d_ws;
    us_t*   WdG   = (us_t*)(ws);                 //       0 .. 524288
    us_t*   decwY = (us_t*)(ws + 524288);        //  524288 .. 557056
    us_t*   EWmG  = (us_t*)(ws + 557056);        //  557056 .. 573440 (16 KB)
    u64_t*  pxb   = (u64_t*)(ws + 573440);       //  573440 .. 581632 (8 KB, 2-parity)
    float*  T     = (float*)(ws + 638976);       //  638976 .. 9027584 (8 MB)
    uint_t* mh32  = (uint_t*)T;                  //  alias: T dead after build_P (4 MB)
    float*  P     = (float*)(ws + 9027584);      // 9027584 .. 25804800 (16 MB)

    cvt_kernel<<<1120, 256, 0, stream>>>(Wdecw, decw, Wencw, bencw,
                                         WdG, decwY, EWmG);
    build_T<<<16384, 128, 0, stream>>>(emb, Wencw, bencw, T);
    build_P<<<32768, 128, 0, stream>>>(T, x0, Wencb, bencb, P);
    // zero the tag mailbox (tag 0 never matches t >= 1)
    (void)hipMemsetAsync(pxb, 0, 8192, stream);
    recur<<<64, 512, 0, stream>>>(bdecw, bdecb, Wdecb, WdG, EWmG,
                                  P, mh32, pxb);
    loss_kernel<<<1024, 256, 0, stream>>>((const us_t*)mh32, decwY, decb, x0, out);
}